// Round 19
// baseline (496.877 us; speedup 1.0000x reference)
//
#include <hip/hip_runtime.h>
#include <stdint.h>

typedef __attribute__((ext_vector_type(8))) short short8;
typedef __attribute__((ext_vector_type(4))) float f32x4;
typedef __attribute__((ext_vector_type(4))) unsigned short us4;

__device__ inline unsigned short f2bf(float f) {
    unsigned u = __float_as_uint(f);
    u = (u + 0x7FFFu + ((u >> 16) & 1u)) >> 16;   // RNE
    return (unsigned short)u;
}

__device__ inline float bf2f(unsigned short u) {
    return __uint_as_float(((unsigned)u) << 16);
}

__device__ inline float gelu_f(float v) {
    return 0.5f * v * (1.0f + erff(v * 0.70710678118654752f));
}

__device__ inline void gload_lds16(const unsigned short* g, const unsigned short* l) {
    __builtin_amdgcn_global_load_lds(
        (const __attribute__((address_space(1))) unsigned int*)(g),
        (__attribute__((address_space(3))) unsigned int*)(l),
        16, 0, 0);
}

// ---------------- elementwise convert x -> bf16 ----------------
__global__ __launch_bounds__(256) void cvt_x_kernel(const float* __restrict__ in,
                                                    unsigned short* __restrict__ out, int n4) {
    int i = blockIdx.x * 256 + threadIdx.x;
    if (i >= n4) return;
    float4 v = reinterpret_cast<const float4*>(in)[i];
    us4 o = { f2bf(v.x), f2bf(v.y), f2bf(v.z), f2bf(v.w) };
    reinterpret_cast<us4*>(out)[i] = o;
}

// ---------------- transpose + convert gate_w [K,N] f32 -> WT [N,K] bf16 ----------------
__global__ __launch_bounds__(256) void transpose_w_kernel(const float* __restrict__ W,
                                                          unsigned short* __restrict__ WT,
                                                          int K, int N) {
    __shared__ float tile[32][33];
    int bn = blockIdx.x * 32;
    int bk = blockIdx.y * 32;
    int tx = threadIdx.x & 31;
    int ty = threadIdx.x >> 5;   // 0..7
#pragma unroll
    for (int j = 0; j < 32; j += 8)
        tile[ty + j][tx] = W[(long long)(bk + ty + j) * N + bn + tx];
    __syncthreads();
#pragma unroll
    for (int j = 0; j < 32; j += 8)
        WT[(long long)(bn + ty + j) * K + bk + tx] = f2bf(tile[tx][ty + j]);
}

// ---------------- block reduction (sum, sumsq); leading sync -> safe to call repeatedly ----
__device__ inline void block_reduce2(float& s, float& q) {
#pragma unroll
    for (int o = 32; o > 0; o >>= 1) {
        s += __shfl_xor(s, o, 64);
        q += __shfl_xor(q, o, 64);
    }
    __shared__ float sh[8];
    __syncthreads();
    int w = threadIdx.x >> 6;
    if ((threadIdx.x & 63) == 0) { sh[w] = s; sh[4 + w] = q; }
    __syncthreads();
    s = (sh[0] + sh[1]) + (sh[2] + sh[3]);
    q = (sh[4] + sh[5]) + (sh[6] + sh[7]);
}

// ---------------- row LayerNorm, D=2048, one block per row (final LN, in-place) ----------
__global__ __launch_bounds__(256) void ln_rows_kernel(const float* __restrict__ in, long long in_stride,
                                                      float* __restrict__ out, long long out_stride,
                                                      const float* __restrict__ gamma,
                                                      const float* __restrict__ beta) {
    const float* p = in + (long long)blockIdx.x * in_stride;
    float* q = out + (long long)blockIdx.x * out_stride;
    int t = threadIdx.x;
    float4 a = reinterpret_cast<const float4*>(p)[t];
    float4 c = reinterpret_cast<const float4*>(p)[t + 256];
    float s  = (a.x + a.y) + (a.z + a.w) + (c.x + c.y) + (c.z + c.w);
    float ss = a.x*a.x + a.y*a.y + a.z*a.z + a.w*a.w
             + c.x*c.x + c.y*c.y + c.z*c.z + c.w*c.w;
    block_reduce2(s, ss);
    const float inv = 1.0f / 2048.0f;
    float mu = s * inv;
    float var = ss * inv - mu * mu;
    float rs = rsqrtf(var + 1e-6f);
    float4 g0 = reinterpret_cast<const float4*>(gamma)[t];
    float4 g1 = reinterpret_cast<const float4*>(gamma)[t + 256];
    float4 b0 = reinterpret_cast<const float4*>(beta)[t];
    float4 b1 = reinterpret_cast<const float4*>(beta)[t + 256];
    float4 o0, o1;
    o0.x = (a.x - mu) * rs * g0.x + b0.x;
    o0.y = (a.y - mu) * rs * g0.y + b0.y;
    o0.z = (a.z - mu) * rs * g0.z + b0.z;
    o0.w = (a.w - mu) * rs * g0.w + b0.w;
    o1.x = (c.x - mu) * rs * g1.x + b1.x;
    o1.y = (c.y - mu) * rs * g1.y + b1.y;
    o1.z = (c.z - mu) * rs * g1.z + b1.z;
    o1.w = (c.w - mu) * rs * g1.w + b1.w;
    reinterpret_cast<float4*>(q)[t] = o0;
    reinterpret_cast<float4*>(q)[t + 256] = o1;
}

// ---------------- fused batch-4 GEMV ----------------
// out[4][N] (+)= f(src)[4][k0:k0+KC] @ W + bias
// MODE 0: raw src rows.  MODE 1: LayerNorm(src rows).
// MODE 3: rows = gelu(srcbias + sum_{y<nY} src[(y*4+r)*sstride + k])  (fused partial-reduce)
// PARTIAL 1: write per-block partials to out[blockIdx.y][4][N] (no bias, no atomics).
// PARTIAL 0: atomicAdd accumulate; blockIdx.y==0 adds bias.
template<int MODE, int PARTIAL>
__global__ __launch_bounds__(256) void gemv4f_kernel(const float* __restrict__ src, long long sstride,
                                                     const float* __restrict__ gamma,
                                                     const float* __restrict__ beta,
                                                     const float* __restrict__ srcbias, int nY,
                                                     const float* __restrict__ W,
                                                     const float* __restrict__ bias,
                                                     float* __restrict__ out,
                                                     int K, int N, int KC) {
    __shared__ float sA[4][128];
    const int tid = threadIdx.x;
    const int k0 = blockIdx.y * KC;

    if (MODE == 1) {
        float mu[4], rsd[4];
#pragma unroll
        for (int r = 0; r < 4; ++r) {
            const float* p = src + r * sstride;
            float s = 0.f, q = 0.f;
            for (int k = tid; k < K; k += 256) { float v = p[k]; s += v; q += v * v; }
            block_reduce2(s, q);
            float m = s / K;
            mu[r] = m;
            rsd[r] = rsqrtf(q / K - m * m + 1e-6f);
        }
        for (int idx = tid; idx < 4 * KC; idx += 256) {
            int r = idx / KC, k = idx - r * KC;
            float v = src[r * sstride + k0 + k];
            sA[r][k] = (v - mu[r]) * rsd[r] * gamma[k0 + k] + beta[k0 + k];
        }
    } else if (MODE == 3) {
        for (int idx = tid; idx < 4 * KC; idx += 256) {
            int r = idx / KC, k = idx - r * KC;
            float acc = srcbias[k0 + k];
#pragma unroll 8
            for (int y = 0; y < nY; ++y)
                acc += src[((long long)(y * 4 + r)) * sstride + k0 + k];
            sA[r][k] = gelu_f(acc);
        }
    } else {
        for (int idx = tid; idx < 4 * KC; idx += 256) {
            int r = idx / KC, k = idx - r * KC;
            sA[r][k] = src[r * sstride + k0 + k];
        }
    }
    __syncthreads();

    const int n4 = blockIdx.x * 256 + tid;
    const int n = n4 * 4;
    const float4* W4 = reinterpret_cast<const float4*>(W);
    float4 a0 = {0.f, 0.f, 0.f, 0.f}, a1 = a0, a2 = a0, a3 = a0;
#pragma unroll 4
    for (int k = 0; k < KC; ++k) {
        float4 w = W4[((long long)(k0 + k) * N + n) >> 2];
        float c0 = sA[0][k], c1 = sA[1][k], c2 = sA[2][k], c3 = sA[3][k];
        a0.x = fmaf(c0, w.x, a0.x); a0.y = fmaf(c0, w.y, a0.y);
        a0.z = fmaf(c0, w.z, a0.z); a0.w = fmaf(c0, w.w, a0.w);
        a1.x = fmaf(c1, w.x, a1.x); a1.y = fmaf(c1, w.y, a1.y);
        a1.z = fmaf(c1, w.z, a1.z); a1.w = fmaf(c1, w.w, a1.w);
        a2.x = fmaf(c2, w.x, a2.x); a2.y = fmaf(c2, w.y, a2.y);
        a2.z = fmaf(c2, w.z, a2.z); a2.w = fmaf(c2, w.w, a2.w);
        a3.x = fmaf(c3, w.x, a3.x); a3.y = fmaf(c3, w.y, a3.y);
        a3.z = fmaf(c3, w.z, a3.z); a3.w = fmaf(c3, w.w, a3.w);
    }

    if (PARTIAL) {
        float4* P4 = reinterpret_cast<float4*>(out);
        const long long pb = (long long)blockIdx.y * 4 * N;
        P4[(pb + 0 * N + n) >> 2] = a0;
        P4[(pb + 1 * N + n) >> 2] = a1;
        P4[(pb + 2 * N + n) >> 2] = a2;
        P4[(pb + 3 * N + n) >> 2] = a3;
        return;
    }

    if (blockIdx.y == 0) {
        float4 b = reinterpret_cast<const float4*>(bias)[n4];
        a0.x += b.x; a0.y += b.y; a0.z += b.z; a0.w += b.w;
        a1.x += b.x; a1.y += b.y; a1.z += b.z; a1.w += b.w;
        a2.x += b.x; a2.y += b.y; a2.z += b.z; a2.w += b.w;
        a3.x += b.x; a3.y += b.y; a3.z += b.z; a3.w += b.w;
    }
    atomicAdd(&out[n + 0], a0.x); atomicAdd(&out[n + 1], a0.y);
    atomicAdd(&out[n + 2], a0.z); atomicAdd(&out[n + 3], a0.w);
    atomicAdd(&out[N + n + 0], a1.x); atomicAdd(&out[N + n + 1], a1.y);
    atomicAdd(&out[N + n + 2], a1.z); atomicAdd(&out[N + n + 3], a1.w);
    atomicAdd(&out[2 * N + n + 0], a2.x); atomicAdd(&out[2 * N + n + 1], a2.y);
    atomicAdd(&out[2 * N + n + 2], a2.z); atomicAdd(&out[2 * N + n + 3], a2.w);
    atomicAdd(&out[3 * N + n + 0], a3.x); atomicAdd(&out[3 * N + n + 1], a3.y);
    atomicAdd(&out[3 * N + n + 2], a3.z); atomicAdd(&out[3 * N + n + 3], a3.w);
}

// ================= 128x128 gate GEMM, 16x16x32 MFMA, 2 blocks/CU, XCD-swizzled =========
// pre = bf2f(x_bf16) + sigmoid(x@gate_w + gate_b) * bcast   (N == K == 2048)
// Measured-best structure (163.2us, MfmaUtil 38.5, 0 conflicts): R16 geometry (8 waves
// 2Mx4N, 512 thr, 64KB LDS, 2 blocks/CU), no sched_barrier (R18: +2.5%), XCD swizzle
// (FETCH 307->205MB). This round: setprio REMOVED -- T5 is null-to-negative on
// barrier-lockstep GEMM schedules (m190: -1.5%), and this K-loop is fully lockstep.
#define BK 64
__global__ __launch_bounds__(512, 4) void gate_gemm_kernel(const unsigned short* __restrict__ A,
                                                           const unsigned short* __restrict__ BT,
                                                           const float* __restrict__ gate_b,
                                                           const float* __restrict__ bcast,
                                                           float* __restrict__ pre,
                                                           int M, int N, int K) {
    extern __shared__ unsigned short lds[];
    const int tid = threadIdx.x;
    const int lane = tid & 63;
    const int wave = tid >> 6;            // 0..7
    const int wm = wave >> 2;             // 0..1  (M half, 64 rows)
    const int wn = wave & 3;              // 0..3  (N quarter, 32 cols)

    const int bid = blockIdx.x;
    const int xcd = bid & 7, seq = bid >> 3;
    const int mp = (seq >> 4) * 8 + xcd;  // 0..127
    const int np = seq & 15;              // 0..15
    const int bm0 = mp * 128;
    const int bn0 = np * 128;
    const int NT = K / BK;                // 32 K-tiles

    const int ch0 = tid, ch1 = tid + 512;
    const int r0 = ch0 >> 3, c0s = (ch0 & 7) ^ (r0 & 7);
    const int r1 = ch1 >> 3, c1s = (ch1 & 7) ^ (r1 & 7);
    const int srcoff0 = r0 * K + c0s * 8;
    const int srcoff1 = r1 * K + c1s * 8;
    const int ldso0 = ch0 * 8;
    const int ldso1 = ch1 * 8;

    const unsigned short* Abase = A + (long long)bm0 * K;
    const unsigned short* Bbase = BT + (long long)bn0 * K;

#define STAGE_A(buf, t)  do { \
        const unsigned short* g = Abase + (t) * BK; \
        const unsigned short* d = &lds[(buf) * 8192]; \
        gload_lds16(g + srcoff0, d + ldso0); \
        gload_lds16(g + srcoff1, d + ldso1); } while (0)
#define STAGE_B(buf, t)  do { \
        const unsigned short* g = Bbase + (t) * BK; \
        const unsigned short* d = &lds[16384 + (buf) * 8192]; \
        gload_lds16(g + srcoff0, d + ldso0); \
        gload_lds16(g + srcoff1, d + ldso1); } while (0)

    f32x4 acc[4][2];
#pragma unroll
    for (int i = 0; i < 4; ++i)
#pragma unroll
        for (int j = 0; j < 2; ++j)
#pragma unroll
            for (int r = 0; r < 4; ++r) acc[i][j][r] = 0.f;

    const int r16 = lane & 15, kq = lane >> 4;

    STAGE_A(0, 0); STAGE_B(0, 0);
    asm volatile("s_waitcnt vmcnt(0)" ::: "memory");
    __builtin_amdgcn_s_barrier();

    for (int t = 0; t < NT; ++t) {
        const int p = t & 1;
        const int u = t + 1;
        const int a_base = p * 8192;
        const int b_base = 16384 + p * 8192;

        if (u < NT) { STAGE_A(1 - p, u); STAGE_B(1 - p, u); }

        short8 bf[2][2];
#pragma unroll
        for (int ni = 0; ni < 2; ++ni) {
            const int rl = wn * 32 + ni * 16 + r16;
#pragma unroll
            for (int kk = 0; kk < 2; ++kk)
                bf[ni][kk] = *reinterpret_cast<const short8*>(
                    &lds[b_base + rl * 64 + (((kk << 2) | kq) ^ (rl & 7)) * 8]);
        }
        short8 af[4][2];
#pragma unroll
        for (int mi = 0; mi < 4; ++mi) {
            const int rl = wm * 64 + mi * 16 + r16;
#pragma unroll
            for (int kk = 0; kk < 2; ++kk)
                af[mi][kk] = *reinterpret_cast<const short8*>(
                    &lds[a_base + rl * 64 + (((kk << 2) | kq) ^ (rl & 7)) * 8]);
        }
#pragma unroll
        for (int mi = 0; mi < 4; ++mi)
#pragma unroll
            for (int ni = 0; ni < 2; ++ni)
#pragma unroll
                for (int kk = 0; kk < 2; ++kk)
                    acc[mi][ni] = __builtin_amdgcn_mfma_f32_16x16x32_bf16(
                        af[mi][kk], bf[ni][kk], acc[mi][ni], 0, 0, 0);
        asm volatile("s_waitcnt vmcnt(0)" ::: "memory");
        __builtin_amdgcn_s_barrier();
    }

    // epilogue: sigmoid gate, residual add (bf16 x), broadcast thought
    const int bnum = bm0 >> 12;               // batch (L=4096)
    const float* bc_row = bcast + (long long)bnum * N;
#pragma unroll
    for (int mi = 0; mi < 4; ++mi) {
        const int row = bm0 + wm * 64 + mi * 16 + kq * 4;
#pragma unroll
        for (int ni = 0; ni < 2; ++ni) {
            const int col = bn0 + wn * 32 + ni * 16 + r16;
            const float gb = gate_b[col];
            const float bc = bc_row[col];
#pragma unroll
            for (int r = 0; r < 4; ++r) {
                const long long off = (long long)(row + r) * N + col;
                const float v = acc[mi][ni][r] + gb;
                const float g = 1.0f / (1.0f + __expf(-v));
                pre[off] = bf2f(A[off]) + g * bc;   // N == K: A[row*K+col] = x[row][col]
            }
        }
    }
}
#undef STAGE_A
#undef STAGE_B

extern "C" void kernel_launch(void* const* d_in, const int* in_sizes, int n_in,
                              void* d_out, int out_size, void* d_ws, size_t ws_size,
                              hipStream_t stream) {
    const float* x         = (const float*)d_in[0];
    const float* in_gamma  = (const float*)d_in[1];
    const float* in_beta   = (const float*)d_in[2];
    const float* agg_w     = (const float*)d_in[3];
    const float* agg_b     = (const float*)d_in[4];
    const float* pn_gamma  = (const float*)d_in[5];
    const float* pn_beta   = (const float*)d_in[6];
    const float* d1_w      = (const float*)d_in[7];
    const float* d1_b      = (const float*)d_in[8];
    const float* d2_w      = (const float*)d_in[9];
    const float* d2_b      = (const float*)d_in[10];
    const float* bc_w      = (const float*)d_in[11];
    const float* bc_b      = (const float*)d_in[12];
    const float* gate_w    = (const float*)d_in[13];
    const float* gate_b    = (const float*)d_in[14];
    const float* out_gamma = (const float*)d_in[15];
    const float* out_beta  = (const float*)d_in[16];

    const int B = 4, L = 4096, D = 2048, H = 8192;
    const int M = B * L;                       // 16384
    float* out = (float*)d_out;

    char* ws = (char*)d_ws;
    unsigned short* xb  = (unsigned short*)ws;                 // 64 MB  bf16 x
    unsigned short* gwT = (unsigned short*)(ws + 67108864);    //  8 MB  bf16 gate_w^T
    float* tbuf  = (float*)(ws + 75497472);                    // [4][D] thought
    float* bcast = tbuf + 4 * D;                               // [4][D]
    float* P1    = bcast + 4 * D;                              // [32][4][H] partials, 4 MB

    // allow 64KB dynamic LDS for the GEMM (idempotent, non-stream call)
    static bool attr_done = false;
    if (!attr_done) {
        hipFuncSetAttribute((const void*)gate_gemm_kernel,
                            hipFuncAttributeMaxDynamicSharedMemorySize, 65536);
        attr_done = true;
    }

    // zero only the atomic-accumulation targets (tbuf + bcast); P1 is fully overwritten
    hipMemsetAsync(tbuf, 0, 8 * D * sizeof(float), stream);

    // ---- thought chain (LN/GELU fused into the gemvs; d1->d2 via coalesced partials) ----
    gemv4f_kernel<1, 0><<<dim3(D / 1024, 64), dim3(256), 0, stream>>>(
        x + (long long)(L - 1) * D, (long long)L * D, in_gamma, in_beta,
        nullptr, 0, agg_w, agg_b, tbuf, D, D, 32);

    for (int s = 0; s < 4; ++s) {
        // d1: LN(tbuf) @ d1_w -> partials P1[32][4][H]  (coalesced stores, no atomics)
        gemv4f_kernel<1, 1><<<dim3(H / 1024, 32), dim3(256), 0, stream>>>(
            tbuf, (long long)D, pn_gamma, pn_beta, nullptr, 0, d1_w, nullptr, P1, D, H, 64);
        // d2: gelu(d1_b + sum P1) @ d2_w -> tbuf (residual accumulate via atomics)
        gemv4f_kernel<3, 0><<<dim3(D / 1024, 128), dim3(256), 0, stream>>>(
            P1, (long long)H, nullptr, nullptr, d1_b, 32, d2_w, d2_b, tbuf, H, D, 64);
    }
    gemv4f_kernel<0, 0><<<dim3(D / 1024, 64), dim3(256), 0, stream>>>(
        tbuf, (long long)D, nullptr, nullptr, nullptr, 0, bc_w, bc_b, bcast, D, D, 32);

    // ---- prepare bf16 operands for the big GEMM ----
    cvt_x_kernel<<<dim3((M * D / 4) / 256), dim3(256), 0, stream>>>(x, xb, M * D / 4);
    transpose_w_kernel<<<dim3(D / 32, D / 32), dim3(256), 0, stream>>>(gate_w, gwT, D, D);

    // ---- fused gate GEMM + sigmoid + residual + broadcast -> d_out (pre-LN) ----
    gate_gemm_kernel<<<dim3((M / 128) * (D / 128)), dim3(512), 65536, stream>>>(
        xb, gwT, gate_b, bcast, out, M, D, D);

    // ---- final LayerNorm in-place on d_out ----
    ln_rows_kernel<<<dim3(M), dim3(256), 0, stream>>>(
        out, (long long)D, out, (long long)D, out_gamma, out_beta);
}

// Round 20
// 495.320 us; speedup vs baseline: 1.0031x; 1.0031x over previous
//
#include <hip/hip_runtime.h>
#include <stdint.h>

typedef __attribute__((ext_vector_type(8))) short short8;
typedef __attribute__((ext_vector_type(4))) float f32x4;
typedef __attribute__((ext_vector_type(4))) unsigned short us4;

__device__ inline unsigned short f2bf(float f) {
    unsigned u = __float_as_uint(f);
    u = (u + 0x7FFFu + ((u >> 16) & 1u)) >> 16;   // RNE
    return (unsigned short)u;
}

__device__ inline float bf2f(unsigned short u) {
    return __uint_as_float(((unsigned)u) << 16);
}

__device__ inline float gelu_f(float v) {
    return 0.5f * v * (1.0f + erff(v * 0.70710678118654752f));
}

__device__ inline void gload_lds16(const unsigned short* g, const unsigned short* l) {
    __builtin_amdgcn_global_load_lds(
        (const __attribute__((address_space(1))) unsigned int*)(g),
        (__attribute__((address_space(3))) unsigned int*)(l),
        16, 0, 0);
}

// ---------------- elementwise convert x -> bf16 ----------------
__global__ __launch_bounds__(256) void cvt_x_kernel(const float* __restrict__ in,
                                                    unsigned short* __restrict__ out, int n4) {
    int i = blockIdx.x * 256 + threadIdx.x;
    if (i >= n4) return;
    float4 v = reinterpret_cast<const float4*>(in)[i];
    us4 o = { f2bf(v.x), f2bf(v.y), f2bf(v.z), f2bf(v.w) };
    reinterpret_cast<us4*>(out)[i] = o;
}

// ---------------- transpose + convert gate_w [K,N] f32 -> WT [N,K] bf16 ----------------
__global__ __launch_bounds__(256) void transpose_w_kernel(const float* __restrict__ W,
                                                          unsigned short* __restrict__ WT,
                                                          int K, int N) {
    __shared__ float tile[32][33];
    int bn = blockIdx.x * 32;
    int bk = blockIdx.y * 32;
    int tx = threadIdx.x & 31;
    int ty = threadIdx.x >> 5;   // 0..7
#pragma unroll
    for (int j = 0; j < 32; j += 8)
        tile[ty + j][tx] = W[(long long)(bk + ty + j) * N + bn + tx];
    __syncthreads();
#pragma unroll
    for (int j = 0; j < 32; j += 8)
        WT[(long long)(bn + ty + j) * K + bk + tx] = f2bf(tile[tx][ty + j]);
}

// ---------------- block reduction (sum, sumsq); leading sync -> safe to call repeatedly ----
__device__ inline void block_reduce2(float& s, float& q) {
#pragma unroll
    for (int o = 32; o > 0; o >>= 1) {
        s += __shfl_xor(s, o, 64);
        q += __shfl_xor(q, o, 64);
    }
    __shared__ float sh[8];
    __syncthreads();
    int w = threadIdx.x >> 6;
    if ((threadIdx.x & 63) == 0) { sh[w] = s; sh[4 + w] = q; }
    __syncthreads();
    s = (sh[0] + sh[1]) + (sh[2] + sh[3]);
    q = (sh[4] + sh[5]) + (sh[6] + sh[7]);
}

// ---------------- row LayerNorm, D=2048, one block per row (final LN, in-place) ----------
__global__ __launch_bounds__(256) void ln_rows_kernel(const float* __restrict__ in, long long in_stride,
                                                      float* __restrict__ out, long long out_stride,
                                                      const float* __restrict__ gamma,
                                                      const float* __restrict__ beta) {
    const float* p = in + (long long)blockIdx.x * in_stride;
    float* q = out + (long long)blockIdx.x * out_stride;
    int t = threadIdx.x;
    float4 a = reinterpret_cast<const float4*>(p)[t];
    float4 c = reinterpret_cast<const float4*>(p)[t + 256];
    float s  = (a.x + a.y) + (a.z + a.w) + (c.x + c.y) + (c.z + c.w);
    float ss = a.x*a.x + a.y*a.y + a.z*a.z + a.w*a.w
             + c.x*c.x + c.y*c.y + c.z*c.z + c.w*c.w;
    block_reduce2(s, ss);
    const float inv = 1.0f / 2048.0f;
    float mu = s * inv;
    float var = ss * inv - mu * mu;
    float rs = rsqrtf(var + 1e-6f);
    float4 g0 = reinterpret_cast<const float4*>(gamma)[t];
    float4 g1 = reinterpret_cast<const float4*>(gamma)[t + 256];
    float4 b0 = reinterpret_cast<const float4*>(beta)[t];
    float4 b1 = reinterpret_cast<const float4*>(beta)[t + 256];
    float4 o0, o1;
    o0.x = (a.x - mu) * rs * g0.x + b0.x;
    o0.y = (a.y - mu) * rs * g0.y + b0.y;
    o0.z = (a.z - mu) * rs * g0.z + b0.z;
    o0.w = (a.w - mu) * rs * g0.w + b0.w;
    o1.x = (c.x - mu) * rs * g1.x + b1.x;
    o1.y = (c.y - mu) * rs * g1.y + b1.y;
    o1.z = (c.z - mu) * rs * g1.z + b1.z;
    o1.w = (c.w - mu) * rs * g1.w + b1.w;
    reinterpret_cast<float4*>(q)[t] = o0;
    reinterpret_cast<float4*>(q)[t + 256] = o1;
}

// ---------------- fused batch-4 GEMV ----------------
// out[4][N] (+)= f(src)[4][k0:k0+KC] @ W + bias
// MODE 0: raw src rows.  MODE 1: LayerNorm(src rows).
// MODE 3: rows = gelu(srcbias + sum_{y<nY} src[(y*4+r)*sstride + k])  (fused partial-reduce)
// PARTIAL 1: write per-block partials to out[blockIdx.y][4][N] (no bias, no atomics).
// PARTIAL 0: atomicAdd accumulate; blockIdx.y==0 adds bias.
template<int MODE, int PARTIAL>
__global__ __launch_bounds__(256) void gemv4f_kernel(const float* __restrict__ src, long long sstride,
                                                     const float* __restrict__ gamma,
                                                     const float* __restrict__ beta,
                                                     const float* __restrict__ srcbias, int nY,
                                                     const float* __restrict__ W,
                                                     const float* __restrict__ bias,
                                                     float* __restrict__ out,
                                                     int K, int N, int KC) {
    __shared__ float sA[4][128];
    const int tid = threadIdx.x;
    const int k0 = blockIdx.y * KC;

    if (MODE == 1) {
        float mu[4], rsd[4];
#pragma unroll
        for (int r = 0; r < 4; ++r) {
            const float* p = src + r * sstride;
            float s = 0.f, q = 0.f;
            for (int k = tid; k < K; k += 256) { float v = p[k]; s += v; q += v * v; }
            block_reduce2(s, q);
            float m = s / K;
            mu[r] = m;
            rsd[r] = rsqrtf(q / K - m * m + 1e-6f);
        }
        for (int idx = tid; idx < 4 * KC; idx += 256) {
            int r = idx / KC, k = idx - r * KC;
            float v = src[r * sstride + k0 + k];
            sA[r][k] = (v - mu[r]) * rsd[r] * gamma[k0 + k] + beta[k0 + k];
        }
    } else if (MODE == 3) {
        for (int idx = tid; idx < 4 * KC; idx += 256) {
            int r = idx / KC, k = idx - r * KC;
            float acc = srcbias[k0 + k];
#pragma unroll 8
            for (int y = 0; y < nY; ++y)
                acc += src[((long long)(y * 4 + r)) * sstride + k0 + k];
            sA[r][k] = gelu_f(acc);
        }
    } else {
        for (int idx = tid; idx < 4 * KC; idx += 256) {
            int r = idx / KC, k = idx - r * KC;
            sA[r][k] = src[r * sstride + k0 + k];
        }
    }
    __syncthreads();

    const int n4 = blockIdx.x * 256 + tid;
    const int n = n4 * 4;
    const float4* W4 = reinterpret_cast<const float4*>(W);
    float4 a0 = {0.f, 0.f, 0.f, 0.f}, a1 = a0, a2 = a0, a3 = a0;
#pragma unroll 4
    for (int k = 0; k < KC; ++k) {
        float4 w = W4[((long long)(k0 + k) * N + n) >> 2];
        float c0 = sA[0][k], c1 = sA[1][k], c2 = sA[2][k], c3 = sA[3][k];
        a0.x = fmaf(c0, w.x, a0.x); a0.y = fmaf(c0, w.y, a0.y);
        a0.z = fmaf(c0, w.z, a0.z); a0.w = fmaf(c0, w.w, a0.w);
        a1.x = fmaf(c1, w.x, a1.x); a1.y = fmaf(c1, w.y, a1.y);
        a1.z = fmaf(c1, w.z, a1.z); a1.w = fmaf(c1, w.w, a1.w);
        a2.x = fmaf(c2, w.x, a2.x); a2.y = fmaf(c2, w.y, a2.y);
        a2.z = fmaf(c2, w.z, a2.z); a2.w = fmaf(c2, w.w, a2.w);
        a3.x = fmaf(c3, w.x, a3.x); a3.y = fmaf(c3, w.y, a3.y);
        a3.z = fmaf(c3, w.z, a3.z); a3.w = fmaf(c3, w.w, a3.w);
    }

    if (PARTIAL) {
        float4* P4 = reinterpret_cast<float4*>(out);
        const long long pb = (long long)blockIdx.y * 4 * N;
        P4[(pb + 0 * N + n) >> 2] = a0;
        P4[(pb + 1 * N + n) >> 2] = a1;
        P4[(pb + 2 * N + n) >> 2] = a2;
        P4[(pb + 3 * N + n) >> 2] = a3;
        return;
    }

    if (blockIdx.y == 0) {
        float4 b = reinterpret_cast<const float4*>(bias)[n4];
        a0.x += b.x; a0.y += b.y; a0.z += b.z; a0.w += b.w;
        a1.x += b.x; a1.y += b.y; a1.z += b.z; a1.w += b.w;
        a2.x += b.x; a2.y += b.y; a2.z += b.z; a2.w += b.w;
        a3.x += b.x; a3.y += b.y; a3.z += b.z; a3.w += b.w;
    }
    atomicAdd(&out[n + 0], a0.x); atomicAdd(&out[n + 1], a0.y);
    atomicAdd(&out[n + 2], a0.z); atomicAdd(&out[n + 3], a0.w);
    atomicAdd(&out[N + n + 0], a1.x); atomicAdd(&out[N + n + 1], a1.y);
    atomicAdd(&out[N + n + 2], a1.z); atomicAdd(&out[N + n + 3], a1.w);
    atomicAdd(&out[2 * N + n + 0], a2.x); atomicAdd(&out[2 * N + n + 1], a2.y);
    atomicAdd(&out[2 * N + n + 2], a2.z); atomicAdd(&out[2 * N + n + 3], a2.w);
    atomicAdd(&out[3 * N + n + 0], a3.x); atomicAdd(&out[3 * N + n + 1], a3.y);
    atomicAdd(&out[3 * N + n + 2], a3.z); atomicAdd(&out[3 * N + n + 3], a3.w);
}

// ================= 128x128 gate GEMM, 16x16x32 MFMA, 2 blocks/CU, XCD-swizzled =========
// pre = bf2f(x_bf16) + sigmoid(x@gate_w + gate_b) * bcast   (N == K == 2048)
// FINAL measured-best config (R18: gate 162.3-164.6us, MfmaUtil 38.5, 0 conflicts):
// 8 waves 2Mx4N, 512 thr, 64KB LDS (2 blocks/CU = 16 waves/CU), XCD swizzle (FETCH
// 307->205MB), no sched_barrier (+2.5% vs R16), setprio PRESENT (R19 A/B: removing it
// cost ~2% -- it arbitrates between the 2 co-resident blocks per CU).
#define BK 64
__global__ __launch_bounds__(512, 4) void gate_gemm_kernel(const unsigned short* __restrict__ A,
                                                           const unsigned short* __restrict__ BT,
                                                           const float* __restrict__ gate_b,
                                                           const float* __restrict__ bcast,
                                                           float* __restrict__ pre,
                                                           int M, int N, int K) {
    extern __shared__ unsigned short lds[];
    const int tid = threadIdx.x;
    const int lane = tid & 63;
    const int wave = tid >> 6;            // 0..7
    const int wm = wave >> 2;             // 0..1  (M half, 64 rows)
    const int wn = wave & 3;              // 0..3  (N quarter, 32 cols)

    const int bid = blockIdx.x;
    const int xcd = bid & 7, seq = bid >> 3;
    const int mp = (seq >> 4) * 8 + xcd;  // 0..127
    const int np = seq & 15;              // 0..15
    const int bm0 = mp * 128;
    const int bn0 = np * 128;
    const int NT = K / BK;                // 32 K-tiles

    const int ch0 = tid, ch1 = tid + 512;
    const int r0 = ch0 >> 3, c0s = (ch0 & 7) ^ (r0 & 7);
    const int r1 = ch1 >> 3, c1s = (ch1 & 7) ^ (r1 & 7);
    const int srcoff0 = r0 * K + c0s * 8;
    const int srcoff1 = r1 * K + c1s * 8;
    const int ldso0 = ch0 * 8;
    const int ldso1 = ch1 * 8;

    const unsigned short* Abase = A + (long long)bm0 * K;
    const unsigned short* Bbase = BT + (long long)bn0 * K;

#define STAGE_A(buf, t)  do { \
        const unsigned short* g = Abase + (t) * BK; \
        const unsigned short* d = &lds[(buf) * 8192]; \
        gload_lds16(g + srcoff0, d + ldso0); \
        gload_lds16(g + srcoff1, d + ldso1); } while (0)
#define STAGE_B(buf, t)  do { \
        const unsigned short* g = Bbase + (t) * BK; \
        const unsigned short* d = &lds[16384 + (buf) * 8192]; \
        gload_lds16(g + srcoff0, d + ldso0); \
        gload_lds16(g + srcoff1, d + ldso1); } while (0)

    f32x4 acc[4][2];
#pragma unroll
    for (int i = 0; i < 4; ++i)
#pragma unroll
        for (int j = 0; j < 2; ++j)
#pragma unroll
            for (int r = 0; r < 4; ++r) acc[i][j][r] = 0.f;

    const int r16 = lane & 15, kq = lane >> 4;

    STAGE_A(0, 0); STAGE_B(0, 0);
    asm volatile("s_waitcnt vmcnt(0)" ::: "memory");
    __builtin_amdgcn_s_barrier();

    for (int t = 0; t < NT; ++t) {
        const int p = t & 1;
        const int u = t + 1;
        const int a_base = p * 8192;
        const int b_base = 16384 + p * 8192;

        if (u < NT) { STAGE_A(1 - p, u); STAGE_B(1 - p, u); }

        short8 bf[2][2];
#pragma unroll
        for (int ni = 0; ni < 2; ++ni) {
            const int rl = wn * 32 + ni * 16 + r16;
#pragma unroll
            for (int kk = 0; kk < 2; ++kk)
                bf[ni][kk] = *reinterpret_cast<const short8*>(
                    &lds[b_base + rl * 64 + (((kk << 2) | kq) ^ (rl & 7)) * 8]);
        }
        short8 af[4][2];
#pragma unroll
        for (int mi = 0; mi < 4; ++mi) {
            const int rl = wm * 64 + mi * 16 + r16;
#pragma unroll
            for (int kk = 0; kk < 2; ++kk)
                af[mi][kk] = *reinterpret_cast<const short8*>(
                    &lds[a_base + rl * 64 + (((kk << 2) | kq) ^ (rl & 7)) * 8]);
        }
        __builtin_amdgcn_s_setprio(1);
#pragma unroll
        for (int mi = 0; mi < 4; ++mi)
#pragma unroll
            for (int ni = 0; ni < 2; ++ni)
#pragma unroll
                for (int kk = 0; kk < 2; ++kk)
                    acc[mi][ni] = __builtin_amdgcn_mfma_f32_16x16x32_bf16(
                        af[mi][kk], bf[ni][kk], acc[mi][ni], 0, 0, 0);
        __builtin_amdgcn_s_setprio(0);
        asm volatile("s_waitcnt vmcnt(0)" ::: "memory");
        __builtin_amdgcn_s_barrier();
    }

    // epilogue: sigmoid gate, residual add (bf16 x), broadcast thought
    const int bnum = bm0 >> 12;               // batch (L=4096)
    const float* bc_row = bcast + (long long)bnum * N;
#pragma unroll
    for (int mi = 0; mi < 4; ++mi) {
        const int row = bm0 + wm * 64 + mi * 16 + kq * 4;
#pragma unroll
        for (int ni = 0; ni < 2; ++ni) {
            const int col = bn0 + wn * 32 + ni * 16 + r16;
            const float gb = gate_b[col];
            const float bc = bc_row[col];
#pragma unroll
            for (int r = 0; r < 4; ++r) {
                const long long off = (long long)(row + r) * N + col;
                const float v = acc[mi][ni][r] + gb;
                const float g = 1.0f / (1.0f + __expf(-v));
                pre[off] = bf2f(A[off]) + g * bc;   // N == K: A[row*K+col] = x[row][col]
            }
        }
    }
}
#undef STAGE_A
#undef STAGE_B

extern "C" void kernel_launch(void* const* d_in, const int* in_sizes, int n_in,
                              void* d_out, int out_size, void* d_ws, size_t ws_size,
                              hipStream_t stream) {
    const float* x         = (const float*)d_in[0];
    const float* in_gamma  = (const float*)d_in[1];
    const float* in_beta   = (const float*)d_in[2];
    const float* agg_w     = (const float*)d_in[3];
    const float* agg_b     = (const float*)d_in[4];
    const float* pn_gamma  = (const float*)d_in[5];
    const float* pn_beta   = (const float*)d_in[6];
    const float* d1_w      = (const float*)d_in[7];
    const float* d1_b      = (const float*)d_in[8];
    const float* d2_w      = (const float*)d_in[9];
    const float* d2_b      = (const float*)d_in[10];
    const float* bc_w      = (const float*)d_in[11];
    const float* bc_b      = (const float*)d_in[12];
    const float* gate_w    = (const float*)d_in[13];
    const float* gate_b    = (const float*)d_in[14];
    const float* out_gamma = (const float*)d_in[15];
    const float* out_beta  = (const float*)d_in[16];

    const int B = 4, L = 4096, D = 2048, H = 8192;
    const int M = B * L;                       // 16384
    float* out = (float*)d_out;

    char* ws = (char*)d_ws;
    unsigned short* xb  = (unsigned short*)ws;                 // 64 MB  bf16 x
    unsigned short* gwT = (unsigned short*)(ws + 67108864);    //  8 MB  bf16 gate_w^T
    float* tbuf  = (float*)(ws + 75497472);                    // [4][D] thought
    float* bcast = tbuf + 4 * D;                               // [4][D]
    float* P1    = bcast + 4 * D;                              // [32][4][H] partials, 4 MB

    // allow 64KB dynamic LDS for the GEMM (idempotent, non-stream call)
    static bool attr_done = false;
    if (!attr_done) {
        hipFuncSetAttribute((const void*)gate_gemm_kernel,
                            hipFuncAttributeMaxDynamicSharedMemorySize, 65536);
        attr_done = true;
    }

    // zero only the atomic-accumulation targets (tbuf + bcast); P1 is fully overwritten
    hipMemsetAsync(tbuf, 0, 8 * D * sizeof(float), stream);

    // ---- thought chain (LN/GELU fused into the gemvs; d1->d2 via coalesced partials) ----
    gemv4f_kernel<1, 0><<<dim3(D / 1024, 64), dim3(256), 0, stream>>>(
        x + (long long)(L - 1) * D, (long long)L * D, in_gamma, in_beta,
        nullptr, 0, agg_w, agg_b, tbuf, D, D, 32);

    for (int s = 0; s < 4; ++s) {
        // d1: LN(tbuf) @ d1_w -> partials P1[32][4][H]  (coalesced stores, no atomics)
        gemv4f_kernel<1, 1><<<dim3(H / 1024, 32), dim3(256), 0, stream>>>(
            tbuf, (long long)D, pn_gamma, pn_beta, nullptr, 0, d1_w, nullptr, P1, D, H, 64);
        // d2: gelu(d1_b + sum P1) @ d2_w -> tbuf (residual accumulate via atomics)
        gemv4f_kernel<3, 0><<<dim3(D / 1024, 128), dim3(256), 0, stream>>>(
            P1, (long long)H, nullptr, nullptr, d1_b, 32, d2_w, d2_b, tbuf, H, D, 64);
    }
    gemv4f_kernel<0, 0><<<dim3(D / 1024, 64), dim3(256), 0, stream>>>(
        tbuf, (long long)D, nullptr, nullptr, nullptr, 0, bc_w, bc_b, bcast, D, D, 32);

    // ---- prepare bf16 operands for the big GEMM ----
    cvt_x_kernel<<<dim3((M * D / 4) / 256), dim3(256), 0, stream>>>(x, xb, M * D / 4);
    transpose_w_kernel<<<dim3(D / 32, D / 32), dim3(256), 0, stream>>>(gate_w, gwT, D, D);

    // ---- fused gate GEMM + sigmoid + residual + broadcast -> d_out (pre-LN) ----
    gate_gemm_kernel<<<dim3((M / 128) * (D / 128)), dim3(512), 65536, stream>>>(
        xb, gwT, gate_b, bcast, out, M, D, D);

    // ---- final LayerNorm in-place on d_out ----
    ln_rows_kernel<<<dim3(M), dim3(256), 0, stream>>>(
        out, (long long)D, out, (long long)D, out_gamma, out_beta);
}